// Round 3
// baseline (401.749 us; speedup 1.0000x reference)
//
#include <hip/hip_runtime.h>
#include <hip/hip_bf16.h>
#include <math.h>

// ANI per-type MLP ensemble, MI355X bf16-MFMA.
// R7: latency attack on the weight stream. R6 showed k_mlp is ~97% stalled
//     (dur identical cold/warm, MfmaUtil 7%, VALU 22%, occ 19%): the per-nt
//     weight load fed its MFMA with no second buffer -> ~184 serial L2 loads
//     per wave. R7 keeps R6's proven structure (2 waves, 2 M-tiles/wave, same
//     LDS arena + barriers + ws layout + epilogue) and adds:
//       - explicit double-buffered weight fragments (wA/wB) per layer: all
//         next-K-step loads issued before current-step MFMA group -> 10-wide
//         MLP, L2 latency hidden behind ~300cyc of MFMA+VALU
//       - 2-deep aev prefetch (rA/rB ping-pong) to cover ~600cyc L3 latency
//       - hardware v_cvt_pk_bf16_f32 for f32->bf16 packing (same RNE bits)
//     Reg budget @L0 peak: 80(w)+32(r)+~80 acc(AGPR)+misc ~= 215 -> 2 w/SIMD,
//     pinned with __launch_bounds__(128,2).

#define NATOMS   131072                     // 2048 * 64
#define NMOL     2048
#define AEV      384
#define NTYPES   4
#define MBLK     64                         // atoms per MLP block
#define PADTOT   (NATOMS + NTYPES * MBLK)   // 131328
#define NBLK_MLP (PADTOT / MBLK)            // 2052
#define NBLK_H   512                        // histogram blocks (256 atoms each)

// swizzled-weight layout (bf16, per type): L0 [12kt][10nt][64][8] = 61440,
// L1 [5][8][64][8] = 20480, L2 [4][6][64][8] = 12288  -> 94208 per type
#define WB_L1 61440
#define WB_L2 81920
#define WB_T  94208

typedef __attribute__((ext_vector_type(8))) short bf16x8;
typedef __attribute__((ext_vector_type(4))) float f32x4;

__device__ __forceinline__ float celu01(float v) {
  return (v > 0.f) ? v : 0.1f * (__expf(v * 10.f) - 1.f);  // v<0 => exp arg <0, safe
}
__device__ __forceinline__ unsigned short f2bf(float x) {  // RNE (bit-exact w/ HW)
  unsigned u = __float_as_uint(x);
  return (unsigned short)((u + 0x7FFFu + ((u >> 16) & 1u)) >> 16);
}
__device__ __forceinline__ unsigned int pk2(float lo, float hi) {  // v_cvt_pk_bf16_f32
  union { __hip_bfloat162 h; unsigned int u; } c;
  c.h = __float22bfloat162_rn(make_float2(lo, hi));  // x -> low 16 bits (RNE)
  return c.u;
}
__device__ __forceinline__ bf16x8 cvt8(const float4 r0, const float4 r1) {
  union { unsigned int u[4]; bf16x8 v; } c;
  c.u[0] = pk2(r0.x, r0.y);
  c.u[1] = pk2(r0.z, r0.w);
  c.u[2] = pk2(r1.x, r1.y);
  c.u[3] = pk2(r1.z, r1.w);
  return c.v;
}

// ---- fused prep: out init + perm init + weight swizzle + histogram ----------

__global__ void k_pre(const int* __restrict__ species, float* __restrict__ out,
                      int* __restrict__ perm, int* __restrict__ hist,
                      const float* __restrict__ W0, const float* __restrict__ W1,
                      const float* __restrict__ W2, unsigned short* __restrict__ WB) {
  const int tid = threadIdx.x, blk = blockIdx.x;
  const int i = blk * 256 + tid;                  // grid = PADTOT/256 = 513
  perm[i] = -1;
  if (i < NATOMS) out[i] = (float)species[i];     // output 0: species passthrough
  if (i < NMOL) out[NATOMS + i] = 0.f;            // output 1: energies

  // weight swizzle, grid-stride over 4*WB_T elements
  for (int f = i; f < NTYPES * WB_T; f += PADTOT) {
    const int t = f / WB_T, e0 = f - t * WB_T;
    int base, NT, N;
    const float* W;
    if (e0 < WB_L1)      { base = 0;     NT = 10; N = 160; W = W0 + (size_t)t * AEV * 160; }
    else if (e0 < WB_L2) { base = WB_L1; NT = 8;  N = 128; W = W1 + (size_t)t * 160 * 128; }
    else                 { base = WB_L2; NT = 6;  N = 96;  W = W2 + (size_t)t * 128 * 96; }
    const int e = e0 - base, frag = e >> 9, r = e & 511, lane = r >> 3, j = r & 7;
    const int kt = frag / NT, nt = frag - kt * NT;
    const int k = kt * 32 + ((lane >> 4) << 3) + j, n = nt * 16 + (lane & 15);
    WB[(size_t)t * WB_T + e0] = f2bf(W[k * N + n]);
  }

  if (blk < NBLK_H) {                             // histogram (blocks 0..511)
    const int sp = species[i];
    const int wv = tid >> 6;
    __shared__ int wc[4 * NTYPES];
#pragma unroll
    for (int t = 0; t < NTYPES; ++t) {
      const unsigned long long m = __ballot(sp == t);
      if ((tid & 63) == 0) wc[wv * NTYPES + t] = __popcll(m);
    }
    __syncthreads();
    if (tid < NTYPES)
      hist[tid * NBLK_H + blk] = wc[tid] + wc[4 + tid] + wc[8 + tid] + wc[12 + tid];
  }
}

// ---- scan + scatter (atomic-free counting sort, unchanged) ------------------

__global__ void k_scan(const int* __restrict__ hist, int* __restrict__ poff,
                       int* __restrict__ boff) {
  __shared__ int tot[NTYPES], base[NTYPES];
  const int tid = threadIdx.x, wv = tid >> 6, lane = tid & 63;
  int s = 0;
  for (int c = 0; c < 8; ++c) s += hist[wv * NBLK_H + c * 64 + lane];
  for (int off = 32; off; off >>= 1) s += __shfl_down(s, off);
  if (lane == 0) tot[wv] = s;
  __syncthreads();
  if (tid == 0) {
    int acc = 0; poff[0] = 0;
    for (int t = 0; t < NTYPES; ++t) {
      base[t] = acc;
      acc += ((tot[t] + 63) >> 6) << 6;
      poff[t + 1] = acc;
    }
  }
  __syncthreads();
  int carry = base[wv];
  for (int c = 0; c < 8; ++c) {
    const int orig = hist[wv * NBLK_H + c * 64 + lane];
    int v = orig;
    for (int off = 1; off < 64; off <<= 1) {
      const int u = __shfl_up(v, off);
      if (lane >= off) v += u;
    }
    boff[wv * NBLK_H + c * 64 + lane] = carry + v - orig;
    carry += __shfl(v, 63);
  }
}

__global__ void k_scatter(const int* __restrict__ species, const int* __restrict__ boff,
                          int* __restrict__ perm) {
  const int tid = threadIdx.x, blk = blockIdx.x;
  const int i = blk * 256 + tid;
  const int sp = species[i];
  const int wv = tid >> 6;
  __shared__ int wc[4 * NTYPES];
  unsigned long long msel = 0;
#pragma unroll
  for (int t = 0; t < NTYPES; ++t) {
    const unsigned long long m = __ballot(sp == t);
    if ((tid & 63) == 0) wc[wv * NTYPES + t] = __popcll(m);
    if (sp == t) msel = m;
  }
  __syncthreads();
  int woff = 0;
  for (int w = 0; w < wv; ++w) woff += wc[w * NTYPES + sp];
  const int rk = __builtin_amdgcn_mbcnt_hi((unsigned)(msel >> 32),
                 __builtin_amdgcn_mbcnt_lo((unsigned)msel, 0));
  perm[boff[sp * NBLK_H + blk] + woff + rk] = i;
}

// ---- 2-wave fused 4-layer MFMA MLP + molecule reduction ---------------------
// 128 threads = 2 waves; wave w owns M-tiles {2w, 2w+1} = rows [32w, 32w+32).
// A-fragments (M=16,K=32 bf16): lane holds row l&15, k = (l>>4)*8 + j, so lanes
// {x,x+16,x+32,x+48} cover one contiguous 128B line of an aev row -> coalesced
// direct global->reg loads, converted f32->bf16 in-register (v_cvt_pk).

__global__ __launch_bounds__(128, 2) void k_mlp(
    const float* __restrict__ aev, const unsigned short* __restrict__ WB,
    const float* __restrict__ b0, const float* __restrict__ b1,
    const float* __restrict__ b2, const float* __restrict__ b3,
    const float* __restrict__ W3,
    const int* __restrict__ poff, const int* __restrict__ perm,
    float* __restrict__ outE)
{
  __shared__ __align__(16) unsigned short H[64 * 168];   // 21504 B
  __shared__ int permS[64];

  const int tid  = threadIdx.x;
  const int lane = tid & 63;
  const int wv   = __builtin_amdgcn_readfirstlane(tid >> 6);   // 0 / 1
  const int quad = lane >> 4, l15 = lane & 15;
  const int slot0 = blockIdx.x * MBLK;

  if (tid < 64) permS[tid] = perm[slot0 + tid];
  int t_ = (slot0 >= poff[1]) + (slot0 >= poff[2]) + (slot0 >= poff[3]);
  if (t_ > 3) t_ = 3;
  const int t = __builtin_amdgcn_readfirstlane(t_);
  __syncthreads();

  // per-M-tile row pointers (padded rows -> aev row 0; results discarded)
  const float* rp[2];
#pragma unroll
  for (int mtl = 0; mtl < 2; ++mtl) {
    const int ai = permS[(2 * wv + mtl) * 16 + l15];
    rp[mtl] = aev + (size_t)(ai < 0 ? 0 : ai) * AEV + quad * 8;
  }

  const bf16x8* wb0 = (const bf16x8*)(WB + (size_t)t * WB_T);
  const bf16x8* wb1 = (const bf16x8*)(WB + (size_t)t * WB_T + WB_L1);
  const bf16x8* wb2 = (const bf16x8*)(WB + (size_t)t * WB_T + WB_L2);

  // ---------------- layer 0: 384 -> 160 --------------------------------------
  f32x4 acc0[10][2];
#pragma unroll
  for (int nt = 0; nt < 10; ++nt) {
    const float b = b0[t * 160 + nt * 16 + l15];
#pragma unroll
    for (int mtl = 0; mtl < 2; ++mtl) acc0[nt][mtl] = (f32x4){b, b, b, b};
  }

  bf16x8 wA[10], wB[10];
  float4 rA[2][2], rB[2][2];
#pragma unroll
  for (int nt = 0; nt < 10; ++nt) wA[nt] = wb0[nt * 64 + lane];   // ks=0 weights
#pragma unroll
  for (int m = 0; m < 2; ++m) {                                    // ks=0,1 aev
    rA[m][0] = *(const float4*)(rp[m]);
    rA[m][1] = *(const float4*)(rp[m] + 4);
    rB[m][0] = *(const float4*)(rp[m] + 32);
    rB[m][1] = *(const float4*)(rp[m] + 36);
  }

  // one K-step: convert current A, prefetch aev ks+2 into same raw buffer,
  // prefetch weights ks+1 into the OTHER buffer, then MFMA on current buffer.
#define L0_STEP(KS, WC, WN, RC, PFW, PFR)                                      \
  {                                                                            \
    const bf16x8 a0 = cvt8(RC[0][0], RC[0][1]);                                \
    const bf16x8 a1 = cvt8(RC[1][0], RC[1][1]);                                \
    if (PFR) {                                                                 \
      _Pragma("unroll")                                                        \
      for (int m = 0; m < 2; ++m) {                                            \
        const float* p = rp[m] + (KS + 2) * 32;                                \
        RC[m][0] = *(const float4*)p;                                          \
        RC[m][1] = *(const float4*)(p + 4);                                    \
      }                                                                        \
    }                                                                          \
    if (PFW) {                                                                 \
      _Pragma("unroll")                                                        \
      for (int nt = 0; nt < 10; ++nt)                                          \
        WN[nt] = wb0[((KS + 1) * 10 + nt) * 64 + lane];                        \
    }                                                                          \
    _Pragma("unroll")                                                          \
    for (int nt = 0; nt < 10; ++nt) {                                          \
      acc0[nt][0] = __builtin_amdgcn_mfma_f32_16x16x32_bf16(a0, WC[nt], acc0[nt][0], 0, 0, 0); \
      acc0[nt][1] = __builtin_amdgcn_mfma_f32_16x16x32_bf16(a1, WC[nt], acc0[nt][1], 0, 0, 0); \
    }                                                                          \
  }

  L0_STEP(0,  wA, wB, rA, 1, 1)
  L0_STEP(1,  wB, wA, rB, 1, 1)
  L0_STEP(2,  wA, wB, rA, 1, 1)
  L0_STEP(3,  wB, wA, rB, 1, 1)
  L0_STEP(4,  wA, wB, rA, 1, 1)
  L0_STEP(5,  wB, wA, rB, 1, 1)
  L0_STEP(6,  wA, wB, rA, 1, 1)
  L0_STEP(7,  wB, wA, rB, 1, 1)
  L0_STEP(8,  wA, wB, rA, 1, 1)
  L0_STEP(9,  wB, wA, rB, 1, 1)   // PFR loads ks=11 into rB
  L0_STEP(10, wA, wB, rA, 1, 0)   // PFW loads ks=11 weights into wB
  L0_STEP(11, wB, wA, rB, 0, 0)
#undef L0_STEP

#pragma unroll
  for (int nt = 0; nt < 10; ++nt)                        // H0: stride 168
#pragma unroll
    for (int mtl = 0; mtl < 2; ++mtl)
#pragma unroll
      for (int r = 0; r < 4; ++r)
        H[((2 * wv + mtl) * 16 + quad * 4 + r) * 168 + nt * 16 + l15] = f2bf(celu01(acc0[nt][mtl][r]));
  __syncthreads();                                       // H0 visible / fence

  // ---------------- layer 1: 160 -> 128 --------------------------------------
  f32x4 acc1[8][2];
#pragma unroll
  for (int nt = 0; nt < 8; ++nt) {
    const float b = b1[t * 128 + nt * 16 + l15];
#pragma unroll
    for (int mtl = 0; mtl < 2; ++mtl) acc1[nt][mtl] = (f32x4){b, b, b, b};
  }
  bf16x8 w1A[8], w1B[8];
#pragma unroll
  for (int nt = 0; nt < 8; ++nt) w1A[nt] = wb1[nt * 64 + lane];

#define L1_STEP(KS, WC, WN, PFW)                                               \
  {                                                                            \
    const bf16x8 a0 = *(const bf16x8*)&H[((2 * wv + 0) * 16 + l15) * 168 + quad * 8 + (KS) * 32]; \
    const bf16x8 a1 = *(const bf16x8*)&H[((2 * wv + 1) * 16 + l15) * 168 + quad * 8 + (KS) * 32]; \
    if (PFW) {                                                                 \
      _Pragma("unroll")                                                        \
      for (int nt = 0; nt < 8; ++nt)                                           \
        WN[nt] = wb1[((KS + 1) * 8 + nt) * 64 + lane];                         \
    }                                                                          \
    _Pragma("unroll")                                                          \
    for (int nt = 0; nt < 8; ++nt) {                                           \
      acc1[nt][0] = __builtin_amdgcn_mfma_f32_16x16x32_bf16(a0, WC[nt], acc1[nt][0], 0, 0, 0); \
      acc1[nt][1] = __builtin_amdgcn_mfma_f32_16x16x32_bf16(a1, WC[nt], acc1[nt][1], 0, 0, 0); \
    }                                                                          \
  }

  L1_STEP(0, w1A, w1B, 1)
  L1_STEP(1, w1B, w1A, 1)
  L1_STEP(2, w1A, w1B, 1)
  L1_STEP(3, w1B, w1A, 1)
  L1_STEP(4, w1A, w1B, 0)
#undef L1_STEP

  __syncthreads();                                       // all H0 reads done
#pragma unroll
  for (int nt = 0; nt < 8; ++nt)                         // H1: stride 136
#pragma unroll
    for (int mtl = 0; mtl < 2; ++mtl)
#pragma unroll
      for (int r = 0; r < 4; ++r)
        H[((2 * wv + mtl) * 16 + quad * 4 + r) * 136 + nt * 16 + l15] = f2bf(celu01(acc1[nt][mtl][r]));
  __syncthreads();                                       // H1 visible / fence

  // ---------------- layer 2: 128 -> 96 ---------------------------------------
  f32x4 acc2[6][2];
#pragma unroll
  for (int nt = 0; nt < 6; ++nt) {
    const float b = b2[t * 96 + nt * 16 + l15];
#pragma unroll
    for (int mtl = 0; mtl < 2; ++mtl) acc2[nt][mtl] = (f32x4){b, b, b, b};
  }
  bf16x8 w2A[6], w2B[6];
#pragma unroll
  for (int nt = 0; nt < 6; ++nt) w2A[nt] = wb2[nt * 64 + lane];

#define L2_STEP(KS, WC, WN, PFW)                                               \
  {                                                                            \
    const bf16x8 a0 = *(const bf16x8*)&H[((2 * wv + 0) * 16 + l15) * 136 + quad * 8 + (KS) * 32]; \
    const bf16x8 a1 = *(const bf16x8*)&H[((2 * wv + 1) * 16 + l15) * 136 + quad * 8 + (KS) * 32]; \
    if (PFW) {                                                                 \
      _Pragma("unroll")                                                        \
      for (int nt = 0; nt < 6; ++nt)                                           \
        WN[nt] = wb2[((KS + 1) * 6 + nt) * 64 + lane];                         \
    }                                                                          \
    _Pragma("unroll")                                                          \
    for (int nt = 0; nt < 6; ++nt) {                                           \
      acc2[nt][0] = __builtin_amdgcn_mfma_f32_16x16x32_bf16(a0, WC[nt], acc2[nt][0], 0, 0, 0); \
      acc2[nt][1] = __builtin_amdgcn_mfma_f32_16x16x32_bf16(a1, WC[nt], acc2[nt][1], 0, 0, 0); \
    }                                                                          \
  }

  L2_STEP(0, w2A, w2B, 1)
  L2_STEP(1, w2B, w2A, 1)
  L2_STEP(2, w2A, w2B, 1)
  L2_STEP(3, w2B, w2A, 0)
#undef L2_STEP

  __syncthreads();                                       // all H1 reads done
#pragma unroll
  for (int nt = 0; nt < 6; ++nt)                         // H2: stride 104
#pragma unroll
    for (int mtl = 0; mtl < 2; ++mtl)
#pragma unroll
      for (int r = 0; r < 4; ++r)
        H[((2 * wv + mtl) * 16 + quad * 4 + r) * 104 + nt * 16 + l15] = f2bf(celu01(acc2[nt][mtl][r]));
  __syncthreads();                                       // H2 visible / fence

  // ---------------- layer 3: 96 -> 1 via MFMA (w3 broadcast to all 16 cols) --
  bf16x8 w3f[3];
#pragma unroll
  for (int ks = 0; ks < 3; ++ks) {
    const float* wp = W3 + t * 96 + ks * 32 + quad * 8;  // uniform across l15
    const float4 f0 = *(const float4*)wp;
    const float4 f1 = *(const float4*)(wp + 4);
    w3f[ks] = cvt8(f0, f1);
  }
  f32x4 accE[2];
#pragma unroll
  for (int mtl = 0; mtl < 2; ++mtl) accE[mtl] = (f32x4){0.f, 0.f, 0.f, 0.f};
#pragma unroll
  for (int mtl = 0; mtl < 2; ++mtl)
#pragma unroll
    for (int ks = 0; ks < 3; ++ks) {
      const bf16x8 a = *(const bf16x8*)&H[((2 * wv + mtl) * 16 + l15) * 104 + quad * 8 + ks * 32];
      accE[mtl] = __builtin_amdgcn_mfma_f32_16x16x32_bf16(a, w3f[ks], accE[mtl], 0, 0, 0);
    }
  // accE[mtl][r] = energy of atom (2wv+mtl)*16 + quad*4 + r, identical over l15
  const float bb3 = b3[t];
#pragma unroll
  for (int mtl = 0; mtl < 2; ++mtl)
#pragma unroll
    for (int r = 0; r < 4; ++r)
      if (l15 == 0) {
        const int ai = permS[(2 * wv + mtl) * 16 + quad * 4 + r];
        if (ai >= 0) atomicAdd(&outE[ai >> 6], accE[mtl][r] + bb3);
      }
}

// ---- launch -----------------------------------------------------------------

extern "C" void kernel_launch(void* const* d_in, const int* in_sizes, int n_in,
                              void* d_out, int out_size, void* d_ws, size_t ws_size,
                              hipStream_t stream)
{
  const int*   species = (const int*)d_in[0];
  const float* aev     = (const float*)d_in[1];
  const float* W0 = (const float*)d_in[2];
  const float* b0 = (const float*)d_in[3];
  const float* W1 = (const float*)d_in[4];
  const float* b1 = (const float*)d_in[5];
  const float* W2 = (const float*)d_in[6];
  const float* b2 = (const float*)d_in[7];
  const float* W3 = (const float*)d_in[8];
  const float* b3 = (const float*)d_in[9];
  float* out = (float*)d_out;

  // ws (ints): poff[8], hist[2048], boff[2048], perm[PADTOT]; then bf16 WB
  int* poff = (int*)d_ws;
  int* hist = poff + 8;
  int* boff = hist + NTYPES * NBLK_H;
  int* perm = boff + NTYPES * NBLK_H;
  unsigned short* WB = (unsigned short*)(perm + PADTOT);

  k_pre    <<<PADTOT / 256, 256, 0, stream>>>(species, out, perm, hist, W0, W1, W2, WB);
  k_scan   <<<1, 256, 0, stream>>>(hist, poff, boff);
  k_scatter<<<NBLK_H, 256, 0, stream>>>(species, boff, perm);
  k_mlp    <<<NBLK_MLP, 128, 0, stream>>>(aev, WB, b0, b1, b2, b3, W3,
                                          poff, perm, out + NATOMS);
}

// Round 4
// 367.262 us; speedup vs baseline: 1.0939x; 1.0939x over previous
//
#include <hip/hip_runtime.h>
#include <hip/hip_bf16.h>
#include <math.h>

// ANI per-type MLP ensemble, MI355X bf16-MFMA.
// R8: weight stream -> LDS via global_load_lds (async DMA), m97 staging pattern.
//     R7 post-mortem: VGPR_Count=76 proved the compiler dissolved the source-
//     level reg double-buffer (160 VGPRs of weight frags can't live in 76) and
//     re-serialized the loads -> regression. Weights cannot be pipelined in
//     VGPRs next to 80 acc regs; buffer them in LDS instead:
//       - per K-step fragment set (10/8/6 KB) DMA'd into a double-buffered
//         LDS arena SHARED by both waves (traffic 755->378 MB, 0 VGPR cost)
//       - step = {issue DMA(ks+1); issue aev prefetch(ks+1); cvt + ds_read(ks)
//         + 20 MFMA; __syncthreads()} -- barrier drain catches loads that flew
//         behind ~200cyc of compute (m97 schedule)
//       - ds_read of a staged frag is lane*16 linear -> conflict-free
//       - last step of each layer stages the next layer's first frag set
//     Unchanged from proven R6: wave/M assignment, H arena (168/136/104),
//     H-phase barriers, epilogue, sort kernels, ws layout.
//     LDS: H 21504 + WL 20480 + permS 256 = 42240 B -> 3 blocks/CU.

#define NATOMS   131072                     // 2048 * 64
#define NMOL     2048
#define AEV      384
#define NTYPES   4
#define MBLK     64                         // atoms per MLP block
#define PADTOT   (NATOMS + NTYPES * MBLK)   // 131328
#define NBLK_MLP (PADTOT / MBLK)            // 2052
#define NBLK_H   512                        // histogram blocks (256 atoms each)

// swizzled-weight layout (bf16, per type): L0 [12kt][10nt][64][8] = 61440,
// L1 [5][8][64][8] = 20480, L2 [4][6][64][8] = 12288  -> 94208 per type
#define WB_L1 61440
#define WB_L2 81920
#define WB_T  94208

typedef __attribute__((ext_vector_type(8))) short bf16x8;
typedef __attribute__((ext_vector_type(4))) float f32x4;

__device__ __forceinline__ float celu01(float v) {
  return (v > 0.f) ? v : 0.1f * (__expf(v * 10.f) - 1.f);  // v<0 => exp arg <0, safe
}
__device__ __forceinline__ unsigned short f2bf(float x) {  // RNE (bit-exact w/ HW)
  unsigned u = __float_as_uint(x);
  return (unsigned short)((u + 0x7FFFu + ((u >> 16) & 1u)) >> 16);
}
__device__ __forceinline__ unsigned int pk2(float lo, float hi) {  // v_cvt_pk_bf16_f32
  union { __hip_bfloat162 h; unsigned int u; } c;
  c.h = __float22bfloat162_rn(make_float2(lo, hi));  // x -> low 16 bits (RNE)
  return c.u;
}
__device__ __forceinline__ bf16x8 cvt8(const float4 r0, const float4 r1) {
  union { unsigned int u[4]; bf16x8 v; } c;
  c.u[0] = pk2(r0.x, r0.y);
  c.u[1] = pk2(r0.z, r0.w);
  c.u[2] = pk2(r1.x, r1.y);
  c.u[3] = pk2(r1.z, r1.w);
  return c.v;
}
// async global->LDS: lane l's 16B from g+l*16B lands at lds_base + l*16B
__device__ __forceinline__ void dma16(const unsigned short* g, unsigned short* l) {
  __builtin_amdgcn_global_load_lds(
      (const __attribute__((address_space(1))) void*)(g),
      (__attribute__((address_space(3))) void*)(l), 16, 0, 0);
}

// ---- fused prep: out init + perm init + weight swizzle + histogram ----------

__global__ void k_pre(const int* __restrict__ species, float* __restrict__ out,
                      int* __restrict__ perm, int* __restrict__ hist,
                      const float* __restrict__ W0, const float* __restrict__ W1,
                      const float* __restrict__ W2, unsigned short* __restrict__ WB) {
  const int tid = threadIdx.x, blk = blockIdx.x;
  const int i = blk * 256 + tid;                  // grid = PADTOT/256 = 513
  perm[i] = -1;
  if (i < NATOMS) out[i] = (float)species[i];     // output 0: species passthrough
  if (i < NMOL) out[NATOMS + i] = 0.f;            // output 1: energies

  // weight swizzle, grid-stride over 4*WB_T elements
  for (int f = i; f < NTYPES * WB_T; f += PADTOT) {
    const int t = f / WB_T, e0 = f - t * WB_T;
    int base, NT, N;
    const float* W;
    if (e0 < WB_L1)      { base = 0;     NT = 10; N = 160; W = W0 + (size_t)t * AEV * 160; }
    else if (e0 < WB_L2) { base = WB_L1; NT = 8;  N = 128; W = W1 + (size_t)t * 160 * 128; }
    else                 { base = WB_L2; NT = 6;  N = 96;  W = W2 + (size_t)t * 128 * 96; }
    const int e = e0 - base, frag = e >> 9, r = e & 511, lane = r >> 3, j = r & 7;
    const int kt = frag / NT, nt = frag - kt * NT;
    const int k = kt * 32 + ((lane >> 4) << 3) + j, n = nt * 16 + (lane & 15);
    WB[(size_t)t * WB_T + e0] = f2bf(W[k * N + n]);
  }

  if (blk < NBLK_H) {                             // histogram (blocks 0..511)
    const int sp = species[i];
    const int wv = tid >> 6;
    __shared__ int wc[4 * NTYPES];
#pragma unroll
    for (int t = 0; t < NTYPES; ++t) {
      const unsigned long long m = __ballot(sp == t);
      if ((tid & 63) == 0) wc[wv * NTYPES + t] = __popcll(m);
    }
    __syncthreads();
    if (tid < NTYPES)
      hist[tid * NBLK_H + blk] = wc[tid] + wc[4 + tid] + wc[8 + tid] + wc[12 + tid];
  }
}

// ---- scan + scatter (atomic-free counting sort, unchanged) ------------------

__global__ void k_scan(const int* __restrict__ hist, int* __restrict__ poff,
                       int* __restrict__ boff) {
  __shared__ int tot[NTYPES], base[NTYPES];
  const int tid = threadIdx.x, wv = tid >> 6, lane = tid & 63;
  int s = 0;
  for (int c = 0; c < 8; ++c) s += hist[wv * NBLK_H + c * 64 + lane];
  for (int off = 32; off; off >>= 1) s += __shfl_down(s, off);
  if (lane == 0) tot[wv] = s;
  __syncthreads();
  if (tid == 0) {
    int acc = 0; poff[0] = 0;
    for (int t = 0; t < NTYPES; ++t) {
      base[t] = acc;
      acc += ((tot[t] + 63) >> 6) << 6;
      poff[t + 1] = acc;
    }
  }
  __syncthreads();
  int carry = base[wv];
  for (int c = 0; c < 8; ++c) {
    const int orig = hist[wv * NBLK_H + c * 64 + lane];
    int v = orig;
    for (int off = 1; off < 64; off <<= 1) {
      const int u = __shfl_up(v, off);
      if (lane >= off) v += u;
    }
    boff[wv * NBLK_H + c * 64 + lane] = carry + v - orig;
    carry += __shfl(v, 63);
  }
}

__global__ void k_scatter(const int* __restrict__ species, const int* __restrict__ boff,
                          int* __restrict__ perm) {
  const int tid = threadIdx.x, blk = blockIdx.x;
  const int i = blk * 256 + tid;
  const int sp = species[i];
  const int wv = tid >> 6;
  __shared__ int wc[4 * NTYPES];
  unsigned long long msel = 0;
#pragma unroll
  for (int t = 0; t < NTYPES; ++t) {
    const unsigned long long m = __ballot(sp == t);
    if ((tid & 63) == 0) wc[wv * NTYPES + t] = __popcll(m);
    if (sp == t) msel = m;
  }
  __syncthreads();
  int woff = 0;
  for (int w = 0; w < wv; ++w) woff += wc[w * NTYPES + sp];
  const int rk = __builtin_amdgcn_mbcnt_hi((unsigned)(msel >> 32),
                 __builtin_amdgcn_mbcnt_lo((unsigned)msel, 0));
  perm[boff[sp * NBLK_H + blk] + woff + rk] = i;
}

// ---- 2-wave fused 4-layer MFMA MLP + molecule reduction ---------------------
// 128 threads = 2 waves; wave w owns M-tiles {2w, 2w+1} = rows [32w, 32w+32).
// Weight fragments (1KB each) staged per K-step into WL[2] (LDS double buffer)
// via global_load_lds, shared by both waves; ds_read at lane*16 (conflict-
// free). A-fragments: per-lane global loads (row l&15, k = quad*8+j -> lanes
// {x,x+16,x+32,x+48} cover one 128B line), cvt f32->bf16 in-register.

__global__ __launch_bounds__(128) void k_mlp(
    const float* __restrict__ aev, const unsigned short* __restrict__ WB,
    const float* __restrict__ b0, const float* __restrict__ b1,
    const float* __restrict__ b2, const float* __restrict__ b3,
    const float* __restrict__ W3,
    const int* __restrict__ poff, const int* __restrict__ perm,
    float* __restrict__ outE)
{
  __shared__ __align__(16) unsigned short H[64 * 168];   // 21504 B
  __shared__ __align__(16) unsigned short WL[2][5120];   // 2 x 10KB weight dbuf
  __shared__ int permS[64];

  const int tid  = threadIdx.x;
  const int lane = tid & 63;
  const int wv   = __builtin_amdgcn_readfirstlane(tid >> 6);   // 0 / 1
  const int quad = lane >> 4, l15 = lane & 15;
  const int slot0 = blockIdx.x * MBLK;

  if (tid < 64) permS[tid] = perm[slot0 + tid];
  int t_ = (slot0 >= poff[1]) + (slot0 >= poff[2]) + (slot0 >= poff[3]);
  if (t_ > 3) t_ = 3;
  const int t = __builtin_amdgcn_readfirstlane(t_);

  const unsigned short* WBt = WB + (size_t)t * WB_T;  // frag f: shorts f*512+lane*8

  // stage L0 ks=0 (frags 0..9; wave wv stages 5) before the first barrier
#pragma unroll
  for (int s = 0; s < 5; ++s)
    dma16(WBt + (wv * 5 + s) * 512 + lane * 8, &WL[0][(wv * 5 + s) * 512]);

  __syncthreads();                       // permS visible + DMA(ks=0) drained

  // per-M-tile row pointers (padded rows -> aev row 0; results discarded)
  const float* rp[2];
#pragma unroll
  for (int mtl = 0; mtl < 2; ++mtl) {
    const int ai = permS[(2 * wv + mtl) * 16 + l15];
    rp[mtl] = aev + (size_t)(ai < 0 ? 0 : ai) * AEV + quad * 8;
  }

  // ---------------- layer 0: 384 -> 160 --------------------------------------
  f32x4 acc0[10][2];
#pragma unroll
  for (int nt = 0; nt < 10; ++nt) {
    const float b = b0[t * 160 + nt * 16 + l15];
#pragma unroll
    for (int mtl = 0; mtl < 2; ++mtl) acc0[nt][mtl] = (f32x4){b, b, b, b};
  }

  float4 raw[2][2];
#pragma unroll
  for (int mtl = 0; mtl < 2; ++mtl) {                    // aev ks=0
    raw[mtl][0] = *(const float4*)(rp[mtl]);
    raw[mtl][1] = *(const float4*)(rp[mtl] + 4);
  }

  for (int ks = 0; ks < 12; ++ks) {
    const int cur = ks & 1;
    const bf16x8 a0 = cvt8(raw[0][0], raw[0][1]);
    const bf16x8 a1 = cvt8(raw[1][0], raw[1][1]);
    if (ks < 11) {
#pragma unroll
      for (int mtl = 0; mtl < 2; ++mtl) {                // aev prefetch ks+1
        const float* p = rp[mtl] + (ks + 1) * 32;
        raw[mtl][0] = *(const float4*)p;
        raw[mtl][1] = *(const float4*)(p + 4);
      }
#pragma unroll
      for (int s = 0; s < 5; ++s)                        // DMA weights ks+1
        dma16(WBt + ((ks + 1) * 10 + wv * 5 + s) * 512 + lane * 8,
              &WL[cur ^ 1][(wv * 5 + s) * 512]);
    } else {                                             // stage L1 ks=0 -> WL[0]
#pragma unroll
      for (int s = 0; s < 4; ++s)
        dma16(WBt + WB_L1 + (wv * 4 + s) * 512 + lane * 8,
              &WL[cur ^ 1][(wv * 4 + s) * 512]);
    }
#pragma unroll
    for (int nt = 0; nt < 10; ++nt) {
      const bf16x8 w = *(const bf16x8*)&WL[cur][nt * 512 + lane * 8];
      acc0[nt][0] = __builtin_amdgcn_mfma_f32_16x16x32_bf16(a0, w, acc0[nt][0], 0, 0, 0);
      acc0[nt][1] = __builtin_amdgcn_mfma_f32_16x16x32_bf16(a1, w, acc0[nt][1], 0, 0, 0);
    }
    __syncthreads();                                     // drain DMA + sync dbuf
  }

#pragma unroll
  for (int nt = 0; nt < 10; ++nt)                        // H0: stride 168
#pragma unroll
    for (int mtl = 0; mtl < 2; ++mtl)
#pragma unroll
      for (int r = 0; r < 4; ++r)
        H[((2 * wv + mtl) * 16 + quad * 4 + r) * 168 + nt * 16 + l15] = f2bf(celu01(acc0[nt][mtl][r]));
  __syncthreads();                                       // H0 visible

  // ---------------- layer 1: 160 -> 128 --------------------------------------
  f32x4 acc1[8][2];
#pragma unroll
  for (int nt = 0; nt < 8; ++nt) {
    const float b = b1[t * 128 + nt * 16 + l15];
#pragma unroll
    for (int mtl = 0; mtl < 2; ++mtl) acc1[nt][mtl] = (f32x4){b, b, b, b};
  }
  for (int ks = 0; ks < 5; ++ks) {
    const int cur = ks & 1;
    const bf16x8 a0 = *(const bf16x8*)&H[((2 * wv + 0) * 16 + l15) * 168 + quad * 8 + ks * 32];
    const bf16x8 a1 = *(const bf16x8*)&H[((2 * wv + 1) * 16 + l15) * 168 + quad * 8 + ks * 32];
    if (ks < 4) {
#pragma unroll
      for (int s = 0; s < 4; ++s)                        // DMA weights ks+1
        dma16(WBt + WB_L1 + ((ks + 1) * 8 + wv * 4 + s) * 512 + lane * 8,
              &WL[cur ^ 1][(wv * 4 + s) * 512]);
    } else {                                             // stage L2 ks=0 -> WL[1]
#pragma unroll
      for (int s = 0; s < 3; ++s)
        dma16(WBt + WB_L2 + (wv * 3 + s) * 512 + lane * 8,
              &WL[cur ^ 1][(wv * 3 + s) * 512]);
    }
#pragma unroll
    for (int nt = 0; nt < 8; ++nt) {
      const bf16x8 w = *(const bf16x8*)&WL[cur][nt * 512 + lane * 8];
      acc1[nt][0] = __builtin_amdgcn_mfma_f32_16x16x32_bf16(a0, w, acc1[nt][0], 0, 0, 0);
      acc1[nt][1] = __builtin_amdgcn_mfma_f32_16x16x32_bf16(a1, w, acc1[nt][1], 0, 0, 0);
    }
    __syncthreads();                                     // drain DMA + all H0 reads done (last iter)
  }
#pragma unroll
  for (int nt = 0; nt < 8; ++nt)                         // H1: stride 136
#pragma unroll
    for (int mtl = 0; mtl < 2; ++mtl)
#pragma unroll
      for (int r = 0; r < 4; ++r)
        H[((2 * wv + mtl) * 16 + quad * 4 + r) * 136 + nt * 16 + l15] = f2bf(celu01(acc1[nt][mtl][r]));
  __syncthreads();                                       // H1 visible

  // ---------------- layer 2: 128 -> 96 ---------------------------------------
  f32x4 acc2[6][2];
#pragma unroll
  for (int nt = 0; nt < 6; ++nt) {
    const float b = b2[t * 96 + nt * 16 + l15];
#pragma unroll
    for (int mtl = 0; mtl < 2; ++mtl) acc2[nt][mtl] = (f32x4){b, b, b, b};
  }
  for (int ks = 0; ks < 4; ++ks) {
    const int cur = (ks + 1) & 1;                        // L2 ks=0 reads WL[1]
    const bf16x8 a0 = *(const bf16x8*)&H[((2 * wv + 0) * 16 + l15) * 136 + quad * 8 + ks * 32];
    const bf16x8 a1 = *(const bf16x8*)&H[((2 * wv + 1) * 16 + l15) * 136 + quad * 8 + ks * 32];
    if (ks < 3) {
#pragma unroll
      for (int s = 0; s < 3; ++s)                        // DMA weights ks+1
        dma16(WBt + WB_L2 + ((ks + 1) * 6 + wv * 3 + s) * 512 + lane * 8,
              &WL[cur ^ 1][(wv * 3 + s) * 512]);
    }
#pragma unroll
    for (int nt = 0; nt < 6; ++nt) {
      const bf16x8 w = *(const bf16x8*)&WL[cur][nt * 512 + lane * 8];
      acc2[nt][0] = __builtin_amdgcn_mfma_f32_16x16x32_bf16(a0, w, acc2[nt][0], 0, 0, 0);
      acc2[nt][1] = __builtin_amdgcn_mfma_f32_16x16x32_bf16(a1, w, acc2[nt][1], 0, 0, 0);
    }
    __syncthreads();                                     // drain DMA + all H1 reads done (last iter)
  }
#pragma unroll
  for (int nt = 0; nt < 6; ++nt)                         // H2: stride 104
#pragma unroll
    for (int mtl = 0; mtl < 2; ++mtl)
#pragma unroll
      for (int r = 0; r < 4; ++r)
        H[((2 * wv + mtl) * 16 + quad * 4 + r) * 104 + nt * 16 + l15] = f2bf(celu01(acc2[nt][mtl][r]));
  __syncthreads();                                       // H2 visible

  // ---------------- layer 3: 96 -> 1 via MFMA (w3 broadcast to all 16 cols) --
  bf16x8 w3f[3];
#pragma unroll
  for (int ks = 0; ks < 3; ++ks) {
    const float* wp = W3 + t * 96 + ks * 32 + quad * 8;  // uniform across l15
    const float4 f0 = *(const float4*)wp;
    const float4 f1 = *(const float4*)(wp + 4);
    w3f[ks] = cvt8(f0, f1);
  }
  f32x4 accE[2];
#pragma unroll
  for (int mtl = 0; mtl < 2; ++mtl) accE[mtl] = (f32x4){0.f, 0.f, 0.f, 0.f};
#pragma unroll
  for (int mtl = 0; mtl < 2; ++mtl)
#pragma unroll
    for (int ks = 0; ks < 3; ++ks) {
      const bf16x8 a = *(const bf16x8*)&H[((2 * wv + mtl) * 16 + l15) * 104 + quad * 8 + ks * 32];
      accE[mtl] = __builtin_amdgcn_mfma_f32_16x16x32_bf16(a, w3f[ks], accE[mtl], 0, 0, 0);
    }
  // accE[mtl][r] = energy of atom (2wv+mtl)*16 + quad*4 + r, identical over l15
  const float bb3 = b3[t];
#pragma unroll
  for (int mtl = 0; mtl < 2; ++mtl)
#pragma unroll
    for (int r = 0; r < 4; ++r)
      if (l15 == 0) {
        const int ai = permS[(2 * wv + mtl) * 16 + quad * 4 + r];
        if (ai >= 0) atomicAdd(&outE[ai >> 6], accE[mtl][r] + bb3);
      }
}

// ---- launch -----------------------------------------------------------------

extern "C" void kernel_launch(void* const* d_in, const int* in_sizes, int n_in,
                              void* d_out, int out_size, void* d_ws, size_t ws_size,
                              hipStream_t stream)
{
  const int*   species = (const int*)d_in[0];
  const float* aev     = (const float*)d_in[1];
  const float* W0 = (const float*)d_in[2];
  const float* b0 = (const float*)d_in[3];
  const float* W1 = (const float*)d_in[4];
  const float* b1 = (const float*)d_in[5];
  const float* W2 = (const float*)d_in[6];
  const float* b2 = (const float*)d_in[7];
  const float* W3 = (const float*)d_in[8];
  const float* b3 = (const float*)d_in[9];
  float* out = (float*)d_out;

  // ws (ints): poff[8], hist[2048], boff[2048], perm[PADTOT]; then bf16 WB
  int* poff = (int*)d_ws;
  int* hist = poff + 8;
  int* boff = hist + NTYPES * NBLK_H;
  int* perm = boff + NTYPES * NBLK_H;
  unsigned short* WB = (unsigned short*)(perm + PADTOT);

  k_pre    <<<PADTOT / 256, 256, 0, stream>>>(species, out, perm, hist, W0, W1, W2, WB);
  k_scan   <<<1, 256, 0, stream>>>(hist, poff, boff);
  k_scatter<<<NBLK_H, 256, 0, stream>>>(species, boff, perm);
  k_mlp    <<<NBLK_MLP, 128, 0, stream>>>(aev, WB, b0, b1, b2, b3, W3,
                                          poff, perm, out + NATOMS);
}